// Round 4
// baseline (135.393 us; speedup 1.0000x reference)
//
#include <hip/hip_runtime.h>

// Problem constants (fixed by reference)
#define BATCH   16384
#define NFEAT   512
#define NTREE   64
#define NDEPTH  6
#define NLEAF   64
#define NDOUT   64
#define NLOGIT  384   // NDEPTH * NTREE

typedef float    f32x4  __attribute__((ext_vector_type(4)));
typedef short    short8 __attribute__((ext_vector_type(8)));
typedef _Float16 half8  __attribute__((ext_vector_type(8)));
typedef _Float16 h2     __attribute__((ext_vector_type(2)));

union U8 { unsigned short u[8]; short8 v; half8 h; };
union HP { _Float16 h[4]; ushort4 u; };
union HS { _Float16 h; unsigned short s; };
union H8 { h2 p[4]; half8 v; };

// fast fp32 -> bf16, round-half-up (+0x8000): 2 VALU ops
__device__ __forceinline__ unsigned short f2bf(float f) {
    union { float f; unsigned int u; } c; c.f = f;
    return (unsigned short)((c.u + 0x8000u) >> 16);
}

__device__ __forceinline__ unsigned short f2h(float f) {
    HS s; s.h = (_Float16)f; return s.s;
}

// async global->LDS DMA, 16B per lane; lds dest must be wave-uniform base,
// HW writes lane i at base + i*16 (m97 pattern).
__device__ __forceinline__ void dma16(const void* g, void* l) {
    __builtin_amdgcn_global_load_lds(
        (const __attribute__((address_space(1))) unsigned int*)g,
        (__attribute__((address_space(3))) unsigned int*)l, 16, 0, 0);
}

// ---------------------------------------------------------------------------
// prep: blocks 0..63    -> V2[t][d][l] = fp16(leaf[t][l][d] / 64)   (f16 MFMA B)
//       blocks 64..159  -> Wt[n][fblk | (g ^ (n&7))*8 ..] = bf16(W[d][f][t])
//       blocks 160..671 -> XC[kb][row][c ^ (row&7)] = bf16(x[row][kb*64+c*8..])
//         pre-converted, pre-swizzled A for gemm1: linear DMA + swizzled
//         ds_read is bank-conflict-free, zero in-loop conversion VALU.
// ---------------------------------------------------------------------------
__global__ __launch_bounds__(256) void prep(const float* __restrict__ leaf,
                                            const float* __restrict__ W,
                                            const float* __restrict__ X,
                                            unsigned short* __restrict__ V2,
                                            unsigned short* __restrict__ Wt,
                                            unsigned short* __restrict__ XC) {
    __shared__ float T[64 * 65];
    const int tid = threadIdx.x;
    if (blockIdx.x < 64) {
        const int t = blockIdx.x;
        const float* src = leaf + (size_t)t * 4096;
        for (int j = 0; j < 4; ++j) {
            int idx = tid + 256 * j;            // 0..1023 float4s
            int l = idx >> 4, d4 = idx & 15;
            float4 v = *(const float4*)(src + l * 64 + d4 * 4);
            T[l * 65 + d4 * 4 + 0] = v.x;
            T[l * 65 + d4 * 4 + 1] = v.y;
            T[l * 65 + d4 * 4 + 2] = v.z;
            T[l * 65 + d4 * 4 + 3] = v.w;
        }
        __syncthreads();
        unsigned short* dst = V2 + (size_t)t * 4096;
        for (int j = 0; j < 4; ++j) {
            int idx = tid + 256 * j;
            int d = idx >> 4, l4 = idx & 15;
            ushort4 u;
            u.x = f2h(T[(l4 * 4 + 0) * 65 + d] * 0.015625f);
            u.y = f2h(T[(l4 * 4 + 1) * 65 + d] * 0.015625f);
            u.z = f2h(T[(l4 * 4 + 2) * 65 + d] * 0.015625f);
            u.w = f2h(T[(l4 * 4 + 3) * 65 + d] * 0.015625f);
            *(ushort4*)(dst + d * 64 + l4 * 4) = u;
        }
    } else if (blockIdx.x < 160) {
        const int bid = blockIdx.x - 64;        // 0..95
        const int d = bid >> 4, f0 = (bid & 15) * 32;
        for (int j = 0; j < 2; ++j) {
            int idx = tid + 256 * j;            // 0..511 float4s (32 f x 64 t)
            int f = idx >> 4, c4 = idx & 15;
            float4 v = *(const float4*)(W + ((size_t)d * 512 + f0 + f) * 64 + c4 * 4);
            T[f * 65 + c4 * 4 + 0] = v.x;
            T[f * 65 + c4 * 4 + 1] = v.y;
            T[f * 65 + c4 * 4 + 2] = v.z;
            T[f * 65 + c4 * 4 + 3] = v.w;
        }
        __syncthreads();
        const int t = tid >> 2, c8 = tid & 3;
        U8 u;
        #pragma unroll
        for (int i = 0; i < 8; ++i) u.u[i] = f2bf(T[(c8 * 8 + i) * 65 + t]);
        // true k-group within this row's 64-block, then XOR-swizzle by n&7
        int g  = ((f0 & 63) >> 3) + c8;         // 0..7
        int gs = g ^ (t & 7);                   // (n&7) == (t&7)
        *(short8*)(Wt + ((size_t)(d * 64 + t)) * 512 + (f0 & ~63) + gs * 8) = u.v;
    } else {
        // x -> bf16, layout XC[kb][row][64], chunk-of-8 XOR-swizzled by row&7
        const int bid = blockIdx.x - 160;       // 0..511
        const int row = bid * 32 + (tid >> 3);
        const int kb  = tid & 7;
        const float* src = X + (size_t)row * NFEAT + kb * 64;
        unsigned short* dst = XC + (size_t)kb * (BATCH * 64) + (size_t)row * 64;
        const int sw = row & 7;
        #pragma unroll
        for (int c = 0; c < 8; ++c) {
            float4 v0 = *(const float4*)(src + c * 8);
            float4 v1 = *(const float4*)(src + c * 8 + 4);
            U8 u;
            u.u[0] = f2bf(v0.x); u.u[1] = f2bf(v0.y);
            u.u[2] = f2bf(v0.z); u.u[3] = f2bf(v0.w);
            u.u[4] = f2bf(v1.x); u.u[5] = f2bf(v1.y);
            u.u[6] = f2bf(v1.z); u.u[7] = f2bf(v1.w);
            *(short8*)(dst + ((c ^ sw) * 8)) = u.v;
        }
    }
}

// ---------------------------------------------------------------------------
// gemm1: SPT[n][b] = fp16(sigmoid(sum_f x[b][f]*W[f][n] + bias[n])), n=d*64+t
// A now pre-converted bf16 (XC, pre-swizzled): no in-loop conversion VALU at
// all; A tile 16 KB, 4 linear DMA/wave. B from pre-swizzled bf16 Wt.
// Grid (128,6) = 768 blocks = 3/CU. LDS 24 KB.
// ---------------------------------------------------------------------------
__global__ __launch_bounds__(256) void gemm1(const unsigned short* __restrict__ XC,
                                             const unsigned short* __restrict__ Wt,
                                             const float* __restrict__ bias,
                                             _Float16* __restrict__ SPT) {
    __shared__ unsigned short SM[12288];      // As[128][64] @0, Bs[64][64] @8192
    unsigned short* As = SM;
    unsigned short* Bs = SM + 8192;
    const int tid  = threadIdx.x;
    const int wave = tid >> 6, lane = tid & 63;
    const int quad = lane >> 4, l15 = lane & 15;
    const int wm = wave & 1, wn = wave >> 1;  // wave covers 64 rows x 32 n
    const int bm = blockIdx.x, bn = blockIdx.y;   // bn == level d

    const int b_r = lane >> 3, b_c = lane & 7;    // B-DMA: 8 rows x 8 chunks

    f32x4 acc[4][2];
    #pragma unroll
    for (int mt = 0; mt < 4; ++mt)
        #pragma unroll
        for (int nt = 0; nt < 2; ++nt)
            acc[mt][nt] = (f32x4){0.f, 0.f, 0.f, 0.f};

    for (int kb = 0; kb < 8; ++kb) {
        // ---- A stage: 4 DMA insts/wave, each 1 KB = 8 rows of 128 B.
        //      XC is pre-swizzled so source chunks are linear.
        #pragma unroll
        for (int i = 0; i < 4; ++i) {
            int rg = wave * 32 + i * 8;
            const unsigned short* g = XC + (size_t)kb * (BATCH * 64)
                                    + (size_t)(bm * 128 + rg + (lane >> 3)) * 64
                                    + (lane & 7) * 8;
            dma16(g, (char*)As + (size_t)rg * 128);
        }
        // ---- B stage: 2 DMA insts/wave, each 1 KB = 8 rows of 128 B (linear;
        //      swizzle pre-baked into Wt)
        #pragma unroll
        for (int i = 0; i < 2; ++i) {
            int nl = wave * 16 + i * 8 + b_r;
            const unsigned short* g = Wt + (size_t)(bn * 64 + nl) * NFEAT + kb * 64 + b_c * 8;
            dma16(g, (char*)Bs + (size_t)(wave * 16 + i * 8) * 128);
        }
        __syncthreads();

        short8 bF[2][2];
        #pragma unroll
        for (int nt = 0; nt < 2; ++nt) {
            int n = wn * 32 + nt * 16 + l15;
            #pragma unroll
            for (int ks = 0; ks < 2; ++ks) {
                int c = (ks * 4 + quad) ^ (n & 7);
                bF[nt][ks] = *(const short8*)(Bs + n * 64 + c * 8);
            }
        }
        short8 aF[4][2];
        #pragma unroll
        for (int mt = 0; mt < 4; ++mt) {
            int r = wm * 64 + mt * 16 + l15;
            #pragma unroll
            for (int ks = 0; ks < 2; ++ks) {
                int c = (ks * 4 + quad) ^ (r & 7);
                aF[mt][ks] = *(const short8*)(As + r * 64 + c * 8);
            }
        }
        #pragma unroll
        for (int mt = 0; mt < 4; ++mt)
            #pragma unroll
            for (int nt = 0; nt < 2; ++nt)
                #pragma unroll
                for (int ks = 0; ks < 2; ++ks)
                    acc[mt][nt] = __builtin_amdgcn_mfma_f32_16x16x32_bf16(
                        aF[mt][ks], bF[nt][ks], acc[mt][nt], 0, 0, 0);
        __syncthreads();   // protect LDS before next stage
    }

    // ---- epilogue: bias + sigmoid -> fp16, transpose via LDS (reuse SM),
    //      then 16B-coalesced stores of SPT[n][b].
    _Float16* Tr = (_Float16*)SM;             // [64 n][136 b-pad] 17.4 KB < 24 KB
    #pragma unroll
    for (int nt = 0; nt < 2; ++nt) {
        int nl = wn * 32 + nt * 16 + l15;
        float bv = bias[bn * 64 + nl];
        #pragma unroll
        for (int mt = 0; mt < 4; ++mt) {
            int bl = wm * 64 + mt * 16 + quad * 4;
            HP h;
            #pragma unroll
            for (int r = 0; r < 4; ++r) {
                float z = acc[mt][nt][r] + bv;
                h.h[r] = (_Float16)(1.0f / (1.0f + __expf(-z)));
            }
            *(ushort4*)(Tr + nl * 136 + bl) = h.u;
        }
    }
    __syncthreads();
    #pragma unroll
    for (int j = 0; j < 4; ++j) {
        int c = tid + 256 * j;                // 0..1023: 64 n x 16 chunks
        int n = c >> 4, off = c & 15;
        uint4 v = *(const uint4*)(Tr + n * 136 + off * 8);
        *(uint4*)((unsigned short*)SPT + (size_t)(bn * 64 + n) * BATCH
                  + bm * 128 + off * 8) = v;
    }
}

// ---------------------------------------------------------------------------
// tree_all: out[b][d] = sum_t sum_l P[b,t,l] * V2[t][d][l]
// P built entirely in packed fp16 (v_pk_mul_f16) from the fp16 probs in LDS;
// feeds mfma_f32_16x16x32_f16 directly. ~70% of the old buildA VALU removed.
// ---------------------------------------------------------------------------
__global__ __launch_bounds__(256) void tree_all(const _Float16* __restrict__ SPT,
                                                const unsigned short* __restrict__ V2,
                                                float* __restrict__ out) {
    __shared__ _Float16 sp[NLOGIT * 32];      // [n][b_loc]          24 KB
    __shared__ _Float16 red[4 * 64 * 40];     // [wave][d][b_loc+pad] 20 KB
    const int tid  = threadIdx.x;
    const int w = tid >> 6, lane = tid & 63;
    const int quad = lane >> 4, l15 = lane & 15;
    const int r0 = blockIdx.x * 32;
    const _Float16* V2h = (const _Float16*)V2;

    // stage split-probs: 384 n-rows x 64 B, 16B chunks
    for (int j = 0; j < 6; ++j) {
        int c = tid + 256 * j;                // 0..1535
        int n = c >> 2, c8 = c & 3;
        *(uint4*)(sp + n * 32 + c8 * 8) =
            *(const uint4*)(SPT + (size_t)n * BATCH + r0 + c8 * 8);
    }
    __syncthreads();

    f32x4 acc[2][4];
    #pragma unroll
    for (int mt = 0; mt < 2; ++mt)
        #pragma unroll
        for (int nt = 0; nt < 4; ++nt)
            acc[mt][nt] = (f32x4){0.f, 0.f, 0.f, 0.f};

    auto loadB = [&](int t, half8 (*bf)[2]) {
        #pragma unroll
        for (int nt = 0; nt < 4; ++nt)
            #pragma unroll
            for (int ks = 0; ks < 2; ++ks)
                bf[nt][ks] = *(const half8*)(V2h + (size_t)t * 4096 +
                                             (nt * 16 + l15) * 64 + ks * 32 + quad * 8);
    };
    auto buildA = [&](int t, half8 (*af)[2]) {
        const _Float16 one = (_Float16)1.0f;
        #pragma unroll
        for (int mt = 0; mt < 2; ++mt) {
            int rl = mt * 16 + l15;
            _Float16 p0 = sp[(0 * 64 + t) * 32 + rl];
            _Float16 p1 = sp[(1 * 64 + t) * 32 + rl];
            _Float16 p2 = sp[(2 * 64 + t) * 32 + rl];
            _Float16 p3 = sp[(3 * 64 + t) * 32 + rl];
            _Float16 p4 = sp[(4 * 64 + t) * 32 + rl];
            _Float16 p5 = sp[(5 * 64 + t) * 32 + rl];
            _Float16 q1 = (quad & 2) ? (_Float16)(one - p1) : p1;
            _Float16 q2 = (quad & 1) ? (_Float16)(one - p2) : p2;
            _Float16 pre  = q1 * q2;
            _Float16 pre0 = p0 * pre;
            _Float16 pre1 = (_Float16)(one - p0) * pre;
            h2 t45 = { p4, (_Float16)(one - p4) };
            h2 t5  = { p5, (_Float16)(one - p5) };
            h2 a34 = (h2){ p3, p3 } * t45;                    // t34[0], t34[1]
            _Float16 q3 = one - p3;
            h2 b34 = (h2){ q3, q3 } * t45;                    // t34[2], t34[3]
            h2 w0 = (h2){ a34.x, a34.x } * t5;
            h2 w1 = (h2){ a34.y, a34.y } * t5;
            h2 w2 = (h2){ b34.x, b34.x } * t5;
            h2 w3 = (h2){ b34.y, b34.y } * t5;
            h2 P0 = { pre0, pre0 }, P1 = { pre1, pre1 };
            H8 a0, a1;
            a0.p[0] = P0 * w0; a0.p[1] = P0 * w1;
            a0.p[2] = P0 * w2; a0.p[3] = P0 * w3;
            a1.p[0] = P1 * w0; a1.p[1] = P1 * w1;
            a1.p[2] = P1 * w2; a1.p[3] = P1 * w3;
            af[mt][0] = a0.v;
            af[mt][1] = a1.v;
        }
    };

    half8 bA[4][2], bB[4][2], aF[2][2];
    loadB(w * 16, bA);
    #pragma unroll 2
    for (int tl = 0; tl < 16; ++tl) {
        const int t = w * 16 + tl;
        half8 (*cur)[2] = (tl & 1) ? bB : bA;
        half8 (*nxt)[2] = (tl & 1) ? bA : bB;
        if (tl + 1 < 16) loadB(t + 1, nxt);   // in flight over aF build
        buildA(t, aF);
        #pragma unroll
        for (int mt = 0; mt < 2; ++mt)
            #pragma unroll
            for (int nt = 0; nt < 4; ++nt)
                #pragma unroll
                for (int ks = 0; ks < 2; ++ks)
                    acc[mt][nt] = __builtin_amdgcn_mfma_f32_16x16x32_f16(
                        aF[mt][ks], cur[nt][ks], acc[mt][nt], 0, 0, 0);
    }

    // cross-wave reduce: write fp16 partials [w][d][b]
    #pragma unroll
    for (int mt = 0; mt < 2; ++mt)
        #pragma unroll
        for (int nt = 0; nt < 4; ++nt) {
            HP h;
            #pragma unroll
            for (int r = 0; r < 4; ++r) h.h[r] = (_Float16)acc[mt][nt][r];
            *(ushort4*)(red + (w * 64 + nt * 16 + l15) * 40 + mt * 16 + quad * 4) = h.u;
        }
    __syncthreads();
    {
        int b = tid >> 3;                     // 0..31
        int doff = (tid & 7) * 8;             // 0..56
        float s[8];
        #pragma unroll
        for (int i = 0; i < 8; ++i) s[i] = 0.f;
        #pragma unroll
        for (int ww = 0; ww < 4; ++ww)
            #pragma unroll
            for (int i = 0; i < 8; ++i)
                s[i] += (float)red[(ww * 64 + doff + i) * 40 + b];
        float4 o0 = { s[0], s[1], s[2], s[3] };
        float4 o1 = { s[4], s[5], s[6], s[7] };
        float* dst = out + (size_t)(r0 + b) * NDOUT + doff;
        *(float4*)dst = o0;
        *(float4*)(dst + 4) = o1;
    }
}

// ---------------------------------------------------------------------------
extern "C" void kernel_launch(void* const* d_in, const int* in_sizes, int n_in,
                              void* d_out, int out_size, void* d_ws, size_t ws_size,
                              hipStream_t stream) {
    const float* x    = (const float*)d_in[0];  // (16384, 512)
    const float* W    = (const float*)d_in[1];  // (6, 512, 64)
    const float* bias = (const float*)d_in[2];  // (6, 64) flat = 384
    const float* leaf = (const float*)d_in[3];  // (64, 64, 64)
    float* out = (float*)d_out;                 // (16384, 64)

    // ws: SPT fp16 [384][16384] (12.58 MB) | V2 fp16 (512 KB) | Wt bf16 (384 KB)
    //   | XC bf16 [8][16384][64] (16.78 MB)
    _Float16* SPT = (_Float16*)d_ws;
    unsigned short* V2 = (unsigned short*)((char*)d_ws + (size_t)NLOGIT * BATCH * 2);
    unsigned short* Wt = V2 + (size_t)NTREE * NLEAF * NDOUT;
    unsigned short* XC = Wt + (size_t)NDEPTH * NFEAT * NTREE;

    prep<<<672, 256, 0, stream>>>(leaf, W, x, V2, Wt, XC);
    gemm1<<<dim3(BATCH / 128, NDEPTH), 256, 0, stream>>>(XC, Wt, bias, SPT);
    tree_all<<<BATCH / 32, 256, 0, stream>>>(SPT, V2, out);
}

// Round 9
// 118.161 us; speedup vs baseline: 1.1458x; 1.1458x over previous
//
#include <hip/hip_runtime.h>

// Problem constants (fixed by reference)
#define BATCH   16384
#define NFEAT   512
#define NTREE   64
#define NDEPTH  6
#define NLEAF   64
#define NDOUT   64
#define NLOGIT  384   // NDEPTH * NTREE

typedef float    f32x4  __attribute__((ext_vector_type(4)));
typedef short    short8 __attribute__((ext_vector_type(8)));
typedef _Float16 half8  __attribute__((ext_vector_type(8)));
typedef _Float16 h2     __attribute__((ext_vector_type(2)));

union U8 { unsigned short u[8]; short8 v; half8 h; };
union HP { _Float16 h[4]; ushort4 u; };
union HS { _Float16 h; unsigned short s; };
union H8 { h2 p[4]; half8 v; };

// fast fp32 -> bf16, round-half-up (+0x8000): 2 VALU ops
__device__ __forceinline__ unsigned short f2bf(float f) {
    union { float f; unsigned int u; } c; c.f = f;
    return (unsigned short)((c.u + 0x8000u) >> 16);
}

__device__ __forceinline__ unsigned short f2h(float f) {
    HS s; s.h = (_Float16)f; return s.s;
}

// async global->LDS DMA, 16B per lane; lds dest must be wave-uniform base,
// HW writes lane i at base + i*16 (m97 pattern).
__device__ __forceinline__ void dma16(const void* g, void* l) {
    __builtin_amdgcn_global_load_lds(
        (const __attribute__((address_space(1))) unsigned int*)g,
        (__attribute__((address_space(3))) unsigned int*)l, 16, 0, 0);
}

// ---------------------------------------------------------------------------
// prep: blocks 0..63  -> V2[t][d][l] = fp16(leaf[t][l][d] / 64)   (f16 MFMA B)
//       blocks 64..159-> Wt[n][fblk | (g ^ (n&7))*8 ..] = bf16(W[d][f][t])
//         n = d*64+t; k-groups of 8 XOR-swizzled by n&7 within each 64-block
//         so fused's linear B-DMA + swizzled ds_read is bank-conflict-free.
// ---------------------------------------------------------------------------
__global__ __launch_bounds__(256) void prep(const float* __restrict__ leaf,
                                            const float* __restrict__ W,
                                            unsigned short* __restrict__ V2,
                                            unsigned short* __restrict__ Wt) {
    __shared__ float T[64 * 65];
    const int tid = threadIdx.x;
    if (blockIdx.x < 64) {
        const int t = blockIdx.x;
        const float* src = leaf + (size_t)t * 4096;
        for (int j = 0; j < 4; ++j) {
            int idx = tid + 256 * j;            // 0..1023 float4s
            int l = idx >> 4, d4 = idx & 15;
            float4 v = *(const float4*)(src + l * 64 + d4 * 4);
            T[l * 65 + d4 * 4 + 0] = v.x;
            T[l * 65 + d4 * 4 + 1] = v.y;
            T[l * 65 + d4 * 4 + 2] = v.z;
            T[l * 65 + d4 * 4 + 3] = v.w;
        }
        __syncthreads();
        unsigned short* dst = V2 + (size_t)t * 4096;
        for (int j = 0; j < 4; ++j) {
            int idx = tid + 256 * j;
            int d = idx >> 4, l4 = idx & 15;
            ushort4 u;
            u.x = f2h(T[(l4 * 4 + 0) * 65 + d] * 0.015625f);
            u.y = f2h(T[(l4 * 4 + 1) * 65 + d] * 0.015625f);
            u.z = f2h(T[(l4 * 4 + 2) * 65 + d] * 0.015625f);
            u.w = f2h(T[(l4 * 4 + 3) * 65 + d] * 0.015625f);
            *(ushort4*)(dst + d * 64 + l4 * 4) = u;
        }
    } else {
        const int bid = blockIdx.x - 64;        // 0..95
        const int d = bid >> 4, f0 = (bid & 15) * 32;
        for (int j = 0; j < 2; ++j) {
            int idx = tid + 256 * j;            // 0..511 float4s (32 f x 64 t)
            int f = idx >> 4, c4 = idx & 15;
            float4 v = *(const float4*)(W + ((size_t)d * 512 + f0 + f) * 64 + c4 * 4);
            T[f * 65 + c4 * 4 + 0] = v.x;
            T[f * 65 + c4 * 4 + 1] = v.y;
            T[f * 65 + c4 * 4 + 2] = v.z;
            T[f * 65 + c4 * 4 + 3] = v.w;
        }
        __syncthreads();
        const int t = tid >> 2, c8 = tid & 3;
        U8 u;
        #pragma unroll
        for (int i = 0; i < 8; ++i) u.u[i] = f2bf(T[(c8 * 8 + i) * 65 + t]);
        // true k-group within this row's 64-block, then XOR-swizzle by n&7
        int g  = ((f0 & 63) >> 3) + c8;         // 0..7
        int gs = g ^ (t & 7);                   // (n&7) == (t&7)
        *(short8*)(Wt + ((size_t)(d * 64 + t)) * 512 + (f0 & ~63) + gs * 8) = u.v;
    }
}

// ---------------------------------------------------------------------------
// fused: per 32 batch rows (512 blocks, 2/CU):
//   phase 1 — logits: 4 waves x 96 n; A (fp32 x, swizzled-source DMA, in-loop
//     bf16 convert — measured-free under the staging barrier) x B (all 384
//     pre-swizzled Wt rows, 48 KB/K-step) -> sigmoid -> sp fp16 in LDS.
//     Kills the SPT 25 MB HBM round-trip, the epilogue transpose, the 6x
//     A re-staging, and one launch.
//   phase 2 — tree: verbatim previous tree_all body (wave w owns 16 trees,
//     packed-fp16 path products, f16 MFMA, cross-wave fp16 reduce).
// LDS: sp 24K | As 8K | Bs 48K ; red (20K) aliases As/Bs in phase 2. 80 KB.
// ---------------------------------------------------------------------------
__global__ __launch_bounds__(256) void fused(const float* __restrict__ x,
                                             const unsigned short* __restrict__ Wt,
                                             const float* __restrict__ bias,
                                             const unsigned short* __restrict__ V2,
                                             float* __restrict__ out) {
    __shared__ char SM[80 * 1024];
    _Float16*       sp = (_Float16*)SM;                    // [384][32]  24 KB
    float*          As = (float*)(SM + 24 * 1024);         // [32][64]    8 KB
    unsigned short* Bs = (unsigned short*)(SM + 32 * 1024);// [384][64]  48 KB
    _Float16*       red = (_Float16*)(SM + 24 * 1024);     // [4][64][40] alias

    const int tid  = threadIdx.x;
    const int w = tid >> 6, lane = tid & 63;
    const int quad = lane >> 4, l15 = lane & 15;
    const int r0 = blockIdx.x * 32;

    // ================= phase 1: logits =================
    f32x4 acc1[2][6];
    #pragma unroll
    for (int mt = 0; mt < 2; ++mt)
        #pragma unroll
        for (int nt = 0; nt < 6; ++nt)
            acc1[mt][nt] = (f32x4){0.f, 0.f, 0.f, 0.f};

    for (int kb = 0; kb < 8; ++kb) {
        // ---- A stage: 8 insts block-wide (2/wave), 1 KB = 4 rows x 256 B.
        //      source chunk XOR-swizzled by row&7 (LDS linear => DMA legal).
        #pragma unroll
        for (int i = 0; i < 2; ++i) {
            int j  = w * 2 + i;
            int rl = j * 4 + (lane >> 4);
            const float* g = x + (size_t)(r0 + rl) * NFEAT + kb * 64
                           + (((lane & 15) ^ ((rl & 7) * 2)) * 4);
            dma16(g, (char*)As + (size_t)j * 1024);
        }
        // ---- B stage: 48 insts block-wide (12/wave), 1 KB = 8 n x 128 B,
        //      linear (swizzle pre-baked into Wt).
        #pragma unroll
        for (int i = 0; i < 12; ++i) {
            int j  = w * 12 + i;
            int nl = j * 8 + (lane >> 3);
            const unsigned short* g = Wt + (size_t)nl * NFEAT + kb * 64 + (lane & 7) * 8;
            dma16(g, (char*)Bs + (size_t)j * 1024);
        }
        __syncthreads();

        short8 aF[2][2];
        #pragma unroll
        for (int mt = 0; mt < 2; ++mt) {
            int r = mt * 16 + l15;
            #pragma unroll
            for (int ks = 0; ks < 2; ++ks) {
                int cb = (ks * 8 + quad * 2) ^ ((r & 7) * 2);
                float4 f0 = *(const float4*)(As + r * 64 + cb * 4);
                float4 f1 = *(const float4*)(As + r * 64 + cb * 4 + 4);
                U8 u;
                u.u[0] = f2bf(f0.x); u.u[1] = f2bf(f0.y);
                u.u[2] = f2bf(f0.z); u.u[3] = f2bf(f0.w);
                u.u[4] = f2bf(f1.x); u.u[5] = f2bf(f1.y);
                u.u[6] = f2bf(f1.z); u.u[7] = f2bf(f1.w);
                aF[mt][ks] = u.v;
            }
        }
        short8 bF[6][2];
        #pragma unroll
        for (int nt = 0; nt < 6; ++nt) {
            int n = w * 96 + nt * 16 + l15;
            #pragma unroll
            for (int ks = 0; ks < 2; ++ks) {
                int c = (ks * 4 + quad) ^ (n & 7);
                bF[nt][ks] = *(const short8*)(Bs + n * 64 + c * 8);
            }
        }
        #pragma unroll
        for (int mt = 0; mt < 2; ++mt)
            #pragma unroll
            for (int nt = 0; nt < 6; ++nt)
                #pragma unroll
                for (int ks = 0; ks < 2; ++ks)
                    acc1[mt][nt] = __builtin_amdgcn_mfma_f32_16x16x32_bf16(
                        aF[mt][ks], bF[nt][ks], acc1[mt][nt], 0, 0, 0);
        __syncthreads();   // protect As/Bs before next stage
    }

    // bias + sigmoid -> sp[n][b_loc] fp16
    #pragma unroll
    for (int nt = 0; nt < 6; ++nt) {
        int n = w * 96 + nt * 16 + l15;
        float bv = bias[n];
        #pragma unroll
        for (int mt = 0; mt < 2; ++mt) {
            HP h;
            #pragma unroll
            for (int r = 0; r < 4; ++r) {
                float z = acc1[mt][nt][r] + bv;
                h.h[r] = (_Float16)(1.0f / (1.0f + __expf(-z)));
            }
            *(ushort4*)(sp + n * 32 + mt * 16 + quad * 4) = h.u;
        }
    }
    __syncthreads();

    // ================= phase 2: tree =================
    const _Float16* V2h = (const _Float16*)V2;

    f32x4 acc[2][4];
    #pragma unroll
    for (int mt = 0; mt < 2; ++mt)
        #pragma unroll
        for (int nt = 0; nt < 4; ++nt)
            acc[mt][nt] = (f32x4){0.f, 0.f, 0.f, 0.f};

    auto loadB = [&](int t, half8 (*bf)[2]) {
        #pragma unroll
        for (int nt = 0; nt < 4; ++nt)
            #pragma unroll
            for (int ks = 0; ks < 2; ++ks)
                bf[nt][ks] = *(const half8*)(V2h + (size_t)t * 4096 +
                                             (nt * 16 + l15) * 64 + ks * 32 + quad * 8);
    };
    auto buildA = [&](int t, half8 (*af)[2]) {
        const _Float16 one = (_Float16)1.0f;
        #pragma unroll
        for (int mt = 0; mt < 2; ++mt) {
            int rl = mt * 16 + l15;
            _Float16 p0 = sp[(0 * 64 + t) * 32 + rl];
            _Float16 p1 = sp[(1 * 64 + t) * 32 + rl];
            _Float16 p2 = sp[(2 * 64 + t) * 32 + rl];
            _Float16 p3 = sp[(3 * 64 + t) * 32 + rl];
            _Float16 p4 = sp[(4 * 64 + t) * 32 + rl];
            _Float16 p5 = sp[(5 * 64 + t) * 32 + rl];
            _Float16 q1 = (quad & 2) ? (_Float16)(one - p1) : p1;
            _Float16 q2 = (quad & 1) ? (_Float16)(one - p2) : p2;
            _Float16 pre  = q1 * q2;
            _Float16 pre0 = p0 * pre;
            _Float16 pre1 = (_Float16)(one - p0) * pre;
            h2 t45 = { p4, (_Float16)(one - p4) };
            h2 t5  = { p5, (_Float16)(one - p5) };
            h2 a34 = (h2){ p3, p3 } * t45;
            _Float16 q3 = one - p3;
            h2 b34 = (h2){ q3, q3 } * t45;
            h2 w0 = (h2){ a34.x, a34.x } * t5;
            h2 w1 = (h2){ a34.y, a34.y } * t5;
            h2 w2 = (h2){ b34.x, b34.x } * t5;
            h2 w3 = (h2){ b34.y, b34.y } * t5;
            h2 P0 = { pre0, pre0 }, P1 = { pre1, pre1 };
            H8 a0, a1;
            a0.p[0] = P0 * w0; a0.p[1] = P0 * w1;
            a0.p[2] = P0 * w2; a0.p[3] = P0 * w3;
            a1.p[0] = P1 * w0; a1.p[1] = P1 * w1;
            a1.p[2] = P1 * w2; a1.p[3] = P1 * w3;
            af[mt][0] = a0.v;
            af[mt][1] = a1.v;
        }
    };

    half8 bA[4][2], bB[4][2], aF2[2][2];
    loadB(w * 16, bA);
    #pragma unroll 2
    for (int tl = 0; tl < 16; ++tl) {
        const int t = w * 16 + tl;
        half8 (*cur)[2] = (tl & 1) ? bB : bA;
        half8 (*nxt)[2] = (tl & 1) ? bA : bB;
        if (tl + 1 < 16) loadB(t + 1, nxt);   // in flight over aF build
        buildA(t, aF2);
        #pragma unroll
        for (int mt = 0; mt < 2; ++mt)
            #pragma unroll
            for (int nt = 0; nt < 4; ++nt)
                #pragma unroll
                for (int ks = 0; ks < 2; ++ks)
                    acc[mt][nt] = __builtin_amdgcn_mfma_f32_16x16x32_f16(
                        aF2[mt][ks], cur[nt][ks], acc[mt][nt], 0, 0, 0);
    }

    // cross-wave reduce: write fp16 partials [w][d][b]  (red aliases As/Bs —
    // phase 2 reads only sp + global V2, so no hazard)
    #pragma unroll
    for (int mt = 0; mt < 2; ++mt)
        #pragma unroll
        for (int nt = 0; nt < 4; ++nt) {
            HP h;
            #pragma unroll
            for (int r = 0; r < 4; ++r) h.h[r] = (_Float16)acc[mt][nt][r];
            *(ushort4*)(red + (w * 64 + nt * 16 + l15) * 40 + mt * 16 + quad * 4) = h.u;
        }
    __syncthreads();
    {
        int b = tid >> 3;                     // 0..31
        int doff = (tid & 7) * 8;             // 0..56
        float s[8];
        #pragma unroll
        for (int i = 0; i < 8; ++i) s[i] = 0.f;
        #pragma unroll
        for (int ww = 0; ww < 4; ++ww)
            #pragma unroll
            for (int i = 0; i < 8; ++i)
                s[i] += (float)red[(ww * 64 + doff + i) * 40 + b];
        float4 o0 = { s[0], s[1], s[2], s[3] };
        float4 o1 = { s[4], s[5], s[6], s[7] };
        float* dst = out + (size_t)(r0 + b) * NDOUT + doff;
        *(float4*)dst = o0;
        *(float4*)(dst + 4) = o1;
    }
}

// ---------------------------------------------------------------------------
extern "C" void kernel_launch(void* const* d_in, const int* in_sizes, int n_in,
                              void* d_out, int out_size, void* d_ws, size_t ws_size,
                              hipStream_t stream) {
    const float* x    = (const float*)d_in[0];  // (16384, 512)
    const float* W    = (const float*)d_in[1];  // (6, 512, 64)
    const float* bias = (const float*)d_in[2];  // (6, 64) flat = 384
    const float* leaf = (const float*)d_in[3];  // (64, 64, 64)
    float* out = (float*)d_out;                 // (16384, 64)

    // ws: V2 fp16 (512 KB) | Wt bf16 (384 KB)
    unsigned short* V2 = (unsigned short*)d_ws;
    unsigned short* Wt = V2 + (size_t)NTREE * NLEAF * NDOUT;

    prep<<<160, 256, 0, stream>>>(leaf, W, V2, Wt);
    fused<<<BATCH / 32, 256, 0, stream>>>(x, Wt, bias, (const unsigned short*)V2, out);
}